// Round 2
// baseline (33.411 us; speedup 1.0000x reference)
//
#include <hip/hip_runtime.h>
#include <math.h>

#define B_    512
#define C_    10
#define HW_   4096
#define NTA   1024      // main kernel: 16 waves/block, 1 block per sample
#define NTF   512       // final kernel threads (one per sample)
#define NBMP  313       // ceil(10^4 / 32) presence-bitmap words

__device__ __forceinline__ float wave_sum_f(float v) {
#pragma unroll
    for (int off = 32; off > 0; off >>= 1) v += __shfl_xor(v, off, 64);
    return v;
}

__global__ __launch_bounds__(NTA, 8) void loss_main(
    const float* __restrict__ pred, const int* __restrict__ tgt,
    const int* __restrict__ inp, const float* __restrict__ strat,
    float* __restrict__ ws)
{
    const int b   = blockIdx.x;
    const int tid = threadIdx.x;

    __shared__ unsigned int s_pred32[HW_ / 4];   // packed pred_idx bytes
    __shared__ unsigned int s_bmp[NBMP];
    __shared__ float        s_red[16][5];
    __shared__ unsigned int s_cmask;

    if (tid < NBMP) s_bmp[tid] = 0u;
    if (tid == 0) s_cmask = 0u;

    const int p = tid << 2;                       // 4 pixels per thread
    const float* pb = pred + (size_t)b * (C_ * HW_) + p;
    const int4 t4 = *(const int4*)(tgt + b * HW_ + p);

    float focal = 0.f;
    unsigned pack = 0u, cmask = 0u;
    int eqc = 0;

    // two rounds of float2 to keep live VGPRs ~40 (occupancy 8 waves/SIMD)
#pragma unroll
    for (int h = 0; h < 2; ++h) {
        float x[C_][2];
#pragma unroll
        for (int c = 0; c < C_; ++c) {
            const float2 v = *(const float2*)(pb + c * HW_ + h * 2);
            x[c][0] = v.x; x[c][1] = v.y;
        }
#pragma unroll
        for (int e2 = 0; e2 < 2; ++e2) {
            const int e = h * 2 + e2;
            const int t = (e == 0) ? t4.x : (e == 1) ? t4.y : (e == 2) ? t4.z : t4.w;
            cmask |= 1u << t;
            float mx = x[0][e2]; int am = 0;
#pragma unroll
            for (int c = 1; c < C_; ++c)
                if (x[c][e2] > mx) { mx = x[c][e2]; am = c; }  // strict >: first max
            float se = 0.f, xt = 0.f;
#pragma unroll
            for (int c = 0; c < C_; ++c) {
                se += __expf(x[c][e2] - mx);
                if (c == t) xt = x[c][e2];
            }
            const float ce = (mx + __logf(se)) - xt;  // -log_softmax[target]
            const float pt = __expf(-ce);             // == exp(xt-mx)/se
            const float om = 1.f - pt;
            focal += om * om * ce;
            eqc += (am == t);
            pack |= (unsigned)am << (8 * e);
        }
    }
    s_pred32[tid] = pack;   // one ds_write_b32, lane i -> dword i (conflict-free)

    // copy-penalty diff count; loaded late to keep main-loop registers low
    const int4 i4 = *(const int4*)(inp + b * HW_ + p);
    const int dfc = ((int)((pack      ) & 0xffu) != i4.x)
                  + ((int)((pack >>  8) & 0xffu) != i4.y)
                  + ((int)((pack >> 16) & 0xffu) != i4.z)
                  + ((int)((pack >> 24) & 0xffu) != i4.w);

    float cre = 0.f;
    if (tid < 128) {
        const float sv = strat[b * 128 + tid];
        cre = 1.f / (1.f + __expf(-sv));
    }

    __syncthreads();   // s_pred32 complete, s_bmp zeroed

    // 2x2-window diversity: thread (r = tid>>4, c4 = (tid&15)*4), one pass
    {
        const int r  = tid >> 4;          // 0..63
        const int c4 = (tid & 15) << 2;   // 0,4,...,60
        if (r < 63) {
            const int di = tid;           // r*16 + (c4>>2) == tid
            const unsigned w0 = s_pred32[di];
            const unsigned w1 = s_pred32[di + 16];
            const unsigned n0 = (c4 < 60) ? s_pred32[di + 1]  : 0u;
            const unsigned n1 = (c4 < 60) ? s_pred32[di + 17] : 0u;
            const unsigned a0 =  w0        & 0xffu, a1 = (w0 >>  8) & 0xffu,
                           a2 = (w0 >> 16) & 0xffu, a3 = (w0 >> 24) & 0xffu,
                           a4 =  n0        & 0xffu;
            const unsigned b0 =  w1        & 0xffu, b1 = (w1 >>  8) & 0xffu,
                           b2 = (w1 >> 16) & 0xffu, b3 = (w1 >> 24) & 0xffu,
                           b4 =  n1        & 0xffu;
            unsigned code;
            code = a0 * 1000u + a1 * 100u + b0 * 10u + b1;
            atomicOr(&s_bmp[code >> 5], 1u << (code & 31u));
            code = a1 * 1000u + a2 * 100u + b1 * 10u + b2;
            atomicOr(&s_bmp[code >> 5], 1u << (code & 31u));
            code = a2 * 1000u + a3 * 100u + b2 * 10u + b3;
            atomicOr(&s_bmp[code >> 5], 1u << (code & 31u));
            if (c4 < 60) {
                code = a3 * 1000u + a4 * 100u + b3 * 10u + b4;
                atomicOr(&s_bmp[code >> 5], 1u << (code & 31u));
            }
        }
    }
    __syncthreads();

    const int nu = (tid < NBMP) ? __popc(s_bmp[tid]) : 0;

    // single reduction round: 5 shfl-reduces + colmask OR, one LDS pass
    const float rf = wave_sum_f(focal);
    const float re = wave_sum_f((float)eqc);
    const float rd = wave_sum_f((float)dfc);
    const float rc = wave_sum_f(cre);
    const float rn = wave_sum_f((float)nu);
#pragma unroll
    for (int off = 32; off > 0; off >>= 1)
        cmask |= (unsigned)__shfl_xor((int)cmask, off, 64);

    const int wv = tid >> 6;
    if ((tid & 63) == 0) {
        s_red[wv][0] = rf; s_red[wv][1] = re; s_red[wv][2] = rd;
        s_red[wv][3] = rc; s_red[wv][4] = rn;
        atomicOr(&s_cmask, cmask);
    }
    __syncthreads();
    if (tid == 0) {
        float F = 0.f, E = 0.f, D = 0.f, CR = 0.f, NU = 0.f;
#pragma unroll
        for (int i = 0; i < 16; ++i) {
            F += s_red[i][0]; E += s_red[i][1]; D += s_red[i][2];
            CR += s_red[i][3]; NU += s_red[i][4];
        }
        const int uc = __popc(s_cmask);
        const float sw = (uc > 3) ? 1.2f : 1.0f;   // strategic weight
        ws[0 * B_ + b] = F * sw;
        ws[1 * B_ + b] = E;                               // intersection
        ws[2 * B_ + b] = (E == 4096.f) ? 1.f : 0.f;       // exact strict
        ws[3 * B_ + b] = (D == 0.f) ? 1.f : 0.f;          // copy flag
        ws[4 * B_ + b] = NU;                              // unique 2x2 codes
        ws[5 * B_ + b] = CR;                              // sigmoid sum
    }
}

// Block-wide sum for the final kernel; result valid on tid==0 only.
__device__ __forceinline__ float block_sum(float v, volatile float* sp, int tid) {
#pragma unroll
    for (int off = 32; off > 0; off >>= 1) v += __shfl_down(v, off, 64);
    __syncthreads();
    if ((tid & 63) == 0) sp[tid >> 6] = v;
    __syncthreads();
    float s = 0.f;
    if (tid == 0) {
#pragma unroll
        for (int i = 0; i < NTF / 64; ++i) s += sp[i];
    }
    return s;
}

__global__ __launch_bounds__(NTF) void loss_final(
    const float* __restrict__ ws, float* __restrict__ out)
{
    const int tid = threadIdx.x;  // == b
    __shared__ float s_red[NTF / 64];

    const float focal_b = ws[0 * B_ + tid];
    const float inter   = ws[1 * B_ + tid];
    const float strict  = ws[2 * B_ + tid];
    const float copyf   = ws[3 * B_ + tid];
    const float nu      = ws[4 * B_ + tid];
    const float cre     = ws[5 * B_ + tid];

    const float iou  = inter * (1.f / 4096.f);
    const float comb = 0.2f * strict + 0.8f * iou;
    const float divb = nu * (1.f / 3969.f);

    const float focal_s = block_sum(focal_b, s_red, tid);
    const float comb_s  = block_sum(comb, s_red, tid);
    const float iou_s   = block_sum(iou, s_red, tid);
    const float copy_s  = block_sum(copyf, s_red, tid);
    const float div_s   = block_sum(divb, s_red, tid);
    const float cre_s   = block_sum(cre, s_red, tid);

    if (tid == 0) {
        const float focal_loss        = focal_s / (512.f * 4096.f);
        const float comb_mean         = comb_s / 512.f;
        const float exact_count       = comb_s;
        const float exact_bonus       = fmaxf(-comb_mean * 5.f, -3.f);
        const float transform_penalty = (copy_s / 512.f) * 0.2f;
        const float creativity        = (cre_s / (512.f * 128.f)) * 0.15f;
        const float diversity         = (div_s / 512.f) * 0.02f;
        const float gcb               = comb_mean * 0.05f;  // grid factor == 1

        float total = focal_loss + transform_penalty + exact_bonus
                    - creativity - diversity - gcb;
        if (isnan(total) || isinf(total)) total = fminf(focal_loss, 10.f);

        out[0] = total;
        out[1] = focal_loss;
        out[2] = transform_penalty;
        out[3] = exact_bonus;
        out[4] = exact_count;
        out[5] = exact_count;   // combined_matches.sum() appears twice
        out[6] = iou_s / 512.f;
        out[7] = creativity;
        out[8] = diversity;
        out[9] = gcb;
    }
}

extern "C" void kernel_launch(void* const* d_in, const int* in_sizes, int n_in,
                              void* d_out, int out_size, void* d_ws, size_t ws_size,
                              hipStream_t stream)
{
    const float* pred  = (const float*)d_in[0];
    const int*   tgt   = (const int*)d_in[1];
    const int*   inp   = (const int*)d_in[2];
    const float* strat = (const float*)d_in[3];
    float* ws  = (float*)d_ws;
    float* out = (float*)d_out;

    hipLaunchKernelGGL(loss_main, dim3(B_), dim3(NTA), 0, stream,
                       pred, tgt, inp, strat, ws);
    hipLaunchKernelGGL(loss_final, dim3(1), dim3(NTF), 0, stream, ws, out);
}